// Round 5
// baseline (329.575 us; speedup 1.0000x reference)
//
#include <hip/hip_runtime.h>
#include <hip/hip_bf16.h>
#include <cstdint>
#include <cstddef>

#define NN 4096
#define FD 256
#define WPR 64  // 64-bit words per adjacency row

typedef __attribute__((ext_vector_type(8))) unsigned short ushort8v;
typedef __attribute__((ext_vector_type(4))) unsigned short ushort4v;
typedef __attribute__((ext_vector_type(8))) short short8;
typedef __attribute__((ext_vector_type(4))) float float4v;

#define C1 30.0f
#define C2 0.3f    // 0.01 * C1

static __device__ __forceinline__ unsigned short f2bf(float x) {
    union { float f; unsigned int u; } v; v.f = x;
    unsigned int r = v.u + 0x7FFFu + ((v.u >> 16) & 1u);
    return (unsigned short)(r >> 16);
}

static __device__ __forceinline__ short8 as_s8(ushort8v v) {
    union { ushort8v u; short8 s; } x; x.u = v; return x.s;
}

// ---------------- fused setup: pack adj + cvt input + cvt weights + zero f1f2 ----------------
__global__ __launch_bounds__(256) void setup(const int* __restrict__ adj,
                                             const float* __restrict__ input,
                                             const float* __restrict__ W0, const float* __restrict__ W1,
                                             const float* __restrict__ W2, const float* __restrict__ W3,
                                             unsigned long long* __restrict__ bits,
                                             unsigned short* __restrict__ hb,
                                             unsigned short* __restrict__ Wbt,
                                             float* __restrict__ f1f2) {
    const int b = blockIdx.x;
    const int t = threadIdx.x;
    if (b < 4096) {
        const int wave = t >> 6, lane = t & 63;
        const int* arow = adj + (size_t)b * NN;
        #pragma unroll
        for (int it = 0; it < NN / 256; ++it) {
            int j = it * 256 + wave * 64 + lane;
            unsigned long long m = __ballot(arow[j] > 0);
            if (lane == 0) bits[(size_t)b * WPR + (it * 4 + wave)] = m;
        }
        hb[(size_t)b * 256 + t] = f2bf(input[(size_t)b * 256 + t]);
    } else if (b < 5120) {
        int idx = (b - 4096) * 256 + t;
        int mat = idx >> 16;
        int within = idx & 65535;
        int n = within >> 8, k = within & 255;
        const float* W = (mat == 0) ? W0 : (mat == 1) ? W1 : (mat == 2) ? W2 : W3;
        Wbt[idx] = f2bf(W[k * 256 + n]);
    } else {
        #pragma unroll
        for (int i = 0; i < 24; ++i) {
            int pos = i * 1024 + (b - 5120) * 256 + t;
            f1f2[pos] = 0.f;
        }
    }
}

// ---------------- projection GEMM, full-K LDS; epilogue: Cbt/Crow + f1/f2 atomics ----------------
__global__ __launch_bounds__(256) void proj_gemm(const unsigned short* __restrict__ A,
                                                 const unsigned short* __restrict__ Bt,
                                                 const float* __restrict__ av,
                                                 float* __restrict__ f1f2,
                                                 unsigned short* __restrict__ Cbt,
                                                 unsigned short* __restrict__ Crow) {
    const int t = threadIdx.x;
    const int bm = blockIdx.x >> 2, bn = blockIdx.x & 3;
    const int m0 = bm * 64, n0 = bn * 64;
    __shared__ unsigned short As[64 * 264];
    __shared__ unsigned short Bs[64 * 264];
    const int lane = t & 63, wave = t >> 6;
    const int wm = (wave >> 1) * 32, wn = (wave & 1) * 32;
    const int lr = t >> 2, lc0 = (t & 3) * 8;
    #pragma unroll
    for (int i = 0; i < 8; ++i) {
        int col = lc0 + i * 32;
        *(ushort8v*)&As[lr * 264 + col] = *(const ushort8v*)&A[(size_t)(m0 + lr) * 256 + col];
        *(ushort8v*)&Bs[lr * 264 + col] = *(const ushort8v*)&Bt[(size_t)(n0 + lr) * 256 + col];
    }
    __syncthreads();
    float4v acc[2][2] = {{{0.f,0.f,0.f,0.f},{0.f,0.f,0.f,0.f}},{{0.f,0.f,0.f,0.f},{0.f,0.f,0.f,0.f}}};
    #pragma unroll
    for (int kk = 0; kk < 256; kk += 32) {
        const int kc = kk + (lane >> 4) * 8;
        #pragma unroll
        for (int fm = 0; fm < 2; ++fm) {
            short8 a = as_s8(*(const ushort8v*)&As[(wm + fm * 16 + (lane & 15)) * 264 + kc]);
            #pragma unroll
            for (int fn = 0; fn < 2; ++fn) {
                short8 b = as_s8(*(const ushort8v*)&Bs[(wn + fn * 16 + (lane & 15)) * 264 + kc]);
                acc[fm][fn] = __builtin_amdgcn_mfma_f32_16x16x32_bf16(a, b, acc[fm][fn], 0, 0, 0);
            }
        }
    }

    const int rb = wm + (lane >> 4) * 4;
    const int cb = wn + (lane & 15);
    if (Crow) {
        #pragma unroll
        for (int fm = 0; fm < 2; ++fm)
            #pragma unroll
            for (int fn = 0; fn < 2; ++fn)
                #pragma unroll
                for (int r = 0; r < 4; ++r)
                    Crow[(size_t)(m0 + rb + fm * 16 + r) * 256 + n0 + cb + fn * 16] = f2bf(acc[fm][fn][r]);
    }

    if (f1f2) {
        float a1c[2], a2c[2];
        #pragma unroll
        for (int fn = 0; fn < 2; ++fn) {
            a1c[fn] = av[n0 + cb + fn * 16];
            a2c[fn] = av[256 + n0 + cb + fn * 16];
        }
        #pragma unroll
        for (int fm = 0; fm < 2; ++fm)
            #pragma unroll
            for (int r = 0; r < 4; ++r) {
                float s1 = acc[fm][0][r] * a1c[0] + acc[fm][1][r] * a1c[1];
                float s2 = acc[fm][0][r] * a2c[0] + acc[fm][1][r] * a2c[1];
                #pragma unroll
                for (int off = 1; off < 16; off <<= 1) {
                    s1 += __shfl_xor(s1, off, 64);
                    s2 += __shfl_xor(s2, off, 64);
                }
                if ((lane & 15) == 0) {
                    int row = m0 + rb + fm * 16 + r;
                    atomicAdd(&f1f2[row], s1);
                    atomicAdd(&f1f2[4096 + row], s2);
                }
            }
    }

    if (Cbt) {
        unsigned short* T = As;
        __syncthreads();
        #pragma unroll
        for (int fm = 0; fm < 2; ++fm)
            #pragma unroll
            for (int fn = 0; fn < 2; ++fn)
                #pragma unroll
                for (int r = 0; r < 4; ++r)
                    T[(cb + fn * 16) * 72 + rb + fm * 16 + r] = f2bf(acc[fm][fn][r]);
        __syncthreads();
        const int tr = t >> 2;
        #pragma unroll
        for (int i = 0; i < 2; ++i) {
            int tc = (t & 3) * 8 + i * 32;
            *(ushort8v*)&Cbt[(size_t)(n0 + tr) * 4096 + m0 + tc] = *(const ushort8v*)&T[tr * 72 + tc];
        }
    }
}

// ---------------- per-row coefficients + global exp tables ----------------
__global__ __launch_bounds__(256) void rowcoef(const unsigned long long* __restrict__ bits,
                                               const float* __restrict__ f1f2,
                                               float4* __restrict__ rowco,
                                               float2* __restrict__ tab2g) {
    __shared__ float2 tl[4096];
    const int t = threadIdx.x;
    const float* f2p = f1f2 + 4096;
    #pragma unroll
    for (int i = 0; i < 16; ++i) {
        float v = f2p[i * 256 + t];
        float2 pr = make_float2(__expf(v - C1), __expf(0.01f * v - C2));
        tl[i * 256 + t] = pr;
        if (blockIdx.x == 0) tab2g[i * 256 + t] = pr;   // one block publishes the table
    }
    __syncthreads();
    const int lane = t & 63, wave = t >> 6;
    for (int rr = 0; rr < 2; ++rr) {
        const int row = blockIdx.x * 8 + wave * 2 + rr;
        const unsigned long long wl = bits[(size_t)row * WPR + lane];
        const float f1r = f1f2[row];
        const float th = __expf(-f1r - C1);
        float mx = 0.f, S1 = 0.f, S2 = 0.f;
        #pragma unroll 16
        for (int b = 0; b < 64; ++b) {
            unsigned long long w = __shfl(wl, b, 64);
            bool bit = (w >> lane) & 1ULL;
            float2 v = tl[b * 64 + lane];
            float ebm = bit ? v.x : 0.f;
            mx = fmaxf(mx, ebm);
            bool cond = v.x > th;
            S1 += (bit && cond)  ? v.x : 0.f;
            S2 += (bit && !cond) ? v.y : 0.f;
        }
        #pragma unroll
        for (int off = 1; off < 64; off <<= 1) {
            mx = fmaxf(mx, __shfl_xor(mx, off, 64));
            S1 += __shfl_xor(S1, off, 64);
            S2 += __shfl_xor(S2, off, 64);
        }
        if (lane == 0) {
            float M  = C1 + __logf(mx);
            float fm_ = f1r + M;
            float m  = fm_ > 0.f ? fm_ : 0.01f * fm_;    // lrelu
            float alpha = __expf(fminf(f1r + C1 - m, 60.f));
            float gamma = __expf(fminf(0.01f * (f1r + C1) - m, 60.f));
            float inv = 1.0f / (alpha * S1 + gamma * S2);
            rowco[row] = make_float4(alpha * inv, gamma * inv, th, 0.f);
        }
    }
}

// ---------------- attention GEMM, split-K, barrier-free: A regenerated per wave in registers ----------------
__global__ __launch_bounds__(256, 2) void att_flat(const unsigned long long* __restrict__ bits,
                                                   const float4* __restrict__ rowco,
                                                   const float2* __restrict__ tab2,
                                                   const unsigned short* __restrict__ Bt,  // Whbt [256][4096]
                                                   float* __restrict__ part, int kchunk) {
    const int t = threadIdx.x;
    const int bm = blockIdx.x & 63;
    const int ks = blockIdx.x >> 6;
    const int m0 = bm * 64;
    const int k0 = ks * kchunk;
    const int lane = t & 63, wave = t >> 6;
    const int wn = wave * 64;
    const int g = lane >> 4, ml = lane & 15;

    float pA[4], pG[4], thE[4];
    #pragma unroll
    for (int fm = 0; fm < 4; ++fm) {
        float4 rc = rowco[m0 + fm * 16 + ml];
        pA[fm] = rc.x; pG[fm] = rc.y; thE[fm] = rc.z;
    }
    const unsigned long long* bitb = bits + (size_t)(m0 + ml) * WPR;
    const unsigned short* bbase = Bt + (size_t)(wn + ml) * 4096 + g * 8;

    float4v acc[4][4];
    #pragma unroll
    for (int i = 0; i < 4; ++i)
        #pragma unroll
        for (int j = 0; j < 4; ++j) acc[i][j] = (float4v){0.f, 0.f, 0.f, 0.f};

    for (int kk = k0; kk < k0 + kchunk; kk += 64) {
        const int word = kk >> 6;
        unsigned long long w64[4];
        #pragma unroll
        for (int fm = 0; fm < 4; ++fm) w64[fm] = bitb[(size_t)(fm * 16) * WPR + word];
        ushort8v breg[4][2];
        #pragma unroll
        for (int fn = 0; fn < 4; ++fn)
            #pragma unroll
            for (int h = 0; h < 2; ++h)
                breg[fn][h] = *(const ushort8v*)&bbase[(size_t)(fn * 16) * 4096 + kk + h * 32];

        #pragma unroll
        for (int h = 0; h < 2; ++h) {
            // (eb,ed) pairs for k = kk + h*32 + g*8 + j, j<8 (L1-hot 512 B slab per block-step)
            float tb[8], td[8];
            const float4v* q = (const float4v*)&tab2[kk + h * 32 + g * 8];
            #pragma unroll
            for (int i = 0; i < 4; ++i) {
                float4v v = q[i];
                tb[2 * i] = v[0]; td[2 * i] = v[1]; tb[2 * i + 1] = v[2]; td[2 * i + 1] = v[3];
            }
            short8 afr[4];
            #pragma unroll
            for (int fm = 0; fm < 4; ++fm) {
                unsigned int wh = (unsigned int)(w64[fm] >> (h * 32 + g * 8));
                ushort8v af;
                #pragma unroll
                for (int jj = 0; jj < 4; ++jj) {
                    float e0 = tb[2 * jj], e1 = tb[2 * jj + 1];
                    float p0 = ((wh >> (2 * jj)) & 1u)     ? (e0 > thE[fm] ? pA[fm] * e0 : pG[fm] * td[2 * jj])     : 0.f;
                    float p1 = ((wh >> (2 * jj + 1)) & 1u) ? (e1 > thE[fm] ? pA[fm] * e1 : pG[fm] * td[2 * jj + 1]) : 0.f;
                    union { __hip_bfloat162 b2; unsigned short us[2]; } cv;
                    cv.b2 = __float22bfloat162_rn(make_float2(p0, p1));
                    af[2 * jj] = cv.us[0]; af[2 * jj + 1] = cv.us[1];
                }
                afr[fm] = as_s8(af);
            }
            #pragma unroll
            for (int fm = 0; fm < 4; ++fm)
                #pragma unroll
                for (int fn = 0; fn < 4; ++fn)
                    acc[fm][fn] = __builtin_amdgcn_mfma_f32_16x16x32_bf16(afr[fm], as_s8(breg[fn][h]), acc[fm][fn], 0, 0, 0);
        }
    }

    const int rb = g * 4;
    const int cb = wn + ml;
    float* pbase = part + ((size_t)ks << 20);
    #pragma unroll
    for (int fm = 0; fm < 4; ++fm)
        #pragma unroll
        for (int fn = 0; fn < 4; ++fn)
            #pragma unroll
            for (int r = 0; r < 4; ++r)
                pbase[(size_t)(m0 + rb + fm * 16 + r) * 256 + cb + fn * 16] = acc[fm][fn][r];
}

// ---------------- reduce split-K partials + ELU (P already normalized) ----------------
__global__ __launch_bounds__(256) void att_reduce(const float* __restrict__ part,
                                                  float* __restrict__ outf,
                                                  unsigned short* __restrict__ hrow, int nsplit) {
    const int idx = (blockIdx.x * 256 + threadIdx.x) * 4;
    float4v s = *(const float4v*)&part[idx];
    for (int sp = 1; sp < nsplit; ++sp)
        s += *(const float4v*)&part[((size_t)sp << 20) + idx];
    float4v v;
    ushort4v hb;
    #pragma unroll
    for (int j = 0; j < 4; ++j) {
        float x = s[j];
        x = x > 0.f ? x : (__expf(x) - 1.f);
        v[j] = x;
        hb[j] = f2bf(x);
    }
    if (outf) *(float4v*)&outf[idx] = v;
    *(ushort4v*)&hrow[idx] = hb;
}

extern "C" void kernel_launch(void* const* d_in, const int* in_sizes, int n_in,
                              void* d_out, int out_size, void* d_ws, size_t ws_size,
                              hipStream_t stream) {
    const float* input = (const float*)d_in[0];
    const int*   adj   = (const int*)d_in[1];
    const float* W0    = (const float*)d_in[2];
    const float* W1    = (const float*)d_in[3];
    const float* a1    = (const float*)d_in[4];
    const float* W2    = (const float*)d_in[5];
    const float* a2    = (const float*)d_in[6];
    const float* W3    = (const float*)d_in[7];
    const float* a3    = (const float*)d_in[8];
    float* out = (float*)d_out;
    char* ws = (char*)d_ws;

    unsigned long long* bits = (unsigned long long*)(ws);                 // 2 MB
    unsigned short* h0   = (unsigned short*)(ws + (2u << 20));            // 2 MB
    unsigned short* h1   = (unsigned short*)(ws + (4u << 20));            // 2 MB
    unsigned short* Whbt = (unsigned short*)(ws + (6u << 20));            // 2 MB
    unsigned short* Wbt  = (unsigned short*)(ws + (8u << 20));            // 512 KB
    float*  f1f2  = (float*)(ws + (9u << 20));                            // 3 layers x 32 KB
    float4* rowco = (float4*)(ws + (10u << 20));                          // 64 KB
    float2* tab2  = (float2*)(ws + (10u << 20) + (256u << 10));           // 32 KB
    float*  part  = (float*)(ws + (13u << 20));                           // 4 MB * SPLIT

    const size_t base = 13u << 20;
    int SPLIT = 8;
    while (SPLIT > 1 && base + (size_t)SPLIT * (4u << 20) > ws_size) SPLIT >>= 1;
    const int kchunk = NN / SPLIT;

    float* f1f2_l[3] = { f1f2, f1f2 + 8192, f1f2 + 16384 };

    setup<<<5124, 256, 0, stream>>>(adj, input, W0, W1, W2, W3, bits, h0, Wbt, f1f2);

    // h = input @ W0 -> h1
    proj_gemm<<<256, 256, 0, stream>>>(h0, Wbt + 0 * 65536, nullptr, nullptr, nullptr, h1);

    // layer 1
    proj_gemm<<<256, 256, 0, stream>>>(h1, Wbt + 1 * 65536, a1, f1f2_l[0], Whbt, nullptr);
    rowcoef<<<512, 256, 0, stream>>>(bits, f1f2_l[0], rowco, tab2);
    att_flat<<<64 * SPLIT, 256, 0, stream>>>(bits, rowco, tab2, Whbt, part, kchunk);
    att_reduce<<<1024, 256, 0, stream>>>(part, nullptr, h0, SPLIT);

    // layer 2
    proj_gemm<<<256, 256, 0, stream>>>(h0, Wbt + 2 * 65536, a2, f1f2_l[1], Whbt, nullptr);
    rowcoef<<<512, 256, 0, stream>>>(bits, f1f2_l[1], rowco, tab2);
    att_flat<<<64 * SPLIT, 256, 0, stream>>>(bits, rowco, tab2, Whbt, part, kchunk);
    att_reduce<<<1024, 256, 0, stream>>>(part, nullptr, h1, SPLIT);

    // layer 3
    proj_gemm<<<256, 256, 0, stream>>>(h1, Wbt + 3 * 65536, a3, f1f2_l[2], Whbt, nullptr);
    rowcoef<<<512, 256, 0, stream>>>(bits, f1f2_l[2], rowco, tab2);
    att_flat<<<64 * SPLIT, 256, 0, stream>>>(bits, rowco, tab2, Whbt, part, kchunk);
    att_reduce<<<1024, 256, 0, stream>>>(part, out, h0, SPLIT);
}